// Round 6
// baseline (115.795 us; speedup 1.0000x reference)
//
#include <hip/hip_runtime.h>
#include <hip/hip_bf16.h>
#include <math.h>

#define T_ 16
#define B_ 1024
#define F_ 512
#define H_ 128
#define D_ 8
#define C_ 100
#define L_ 512
#define CP_ 112   // C padded to multiple of 16 for MFMA N

typedef __attribute__((ext_vector_type(8))) short bf16x8_t;
typedef __attribute__((ext_vector_type(4))) float f32x4_t;

__device__ inline ushort f2bf(float x) {
  __hip_bfloat16 b = __float2bfloat16(x);
  return *(ushort*)&b;
}
__device__ inline float bf2f(ushort u) {
  union { unsigned int i; float f; } v;
  v.i = ((unsigned int)u) << 16;
  return v.f;
}

// ---------------------------------------------------------------------------
// k_prep: round-3 version (fastest measured).  Block-range dispatch:
//   [0,256)      : feat fp32 -> bf16
//   [256,1280)   : W1 [t][F][H] -> W1T [t][H][F] bf16
//   [1280,2304)  : W2 [t][H][L] -> W2T [t][L][H] bf16
//   [2304,2560)  : softmax(pi) -> lpT[t][c][l], 256 blocks x 32 rows,
//                  coalesced 16B stores.
// ---------------------------------------------------------------------------
__global__ __launch_bounds__(256) void k_prep(
    const float* __restrict__ feat, const float* __restrict__ W1,
    const float* __restrict__ W2, const float* __restrict__ pi,
    ushort* __restrict__ feat_bf, ushort* __restrict__ W1T,
    ushort* __restrict__ W2T, ushort* __restrict__ lpT) {
  __shared__ ushort ubuf[112 * 48];                  // 10752 B, aliased
  float (*tile)[33] = (float(*)[33])ubuf;            // transpose path (4224 B)
  ushort (*tileT)[48] = (ushort(*)[48])ubuf;         // softmax path
  const int bid = blockIdx.x, tid = threadIdx.x;

  if (bid < 256) {  // ---- feat cvt
    int i = (bid * 256 + tid) * 8;
    float4 a = *(const float4*)(feat + i);
    float4 b = *(const float4*)(feat + i + 4);
    bf16x8_t o;
    o[0] = (short)f2bf(a.x); o[1] = (short)f2bf(a.y);
    o[2] = (short)f2bf(a.z); o[3] = (short)f2bf(a.w);
    o[4] = (short)f2bf(b.x); o[5] = (short)f2bf(b.y);
    o[6] = (short)f2bf(b.z); o[7] = (short)f2bf(b.w);
    *(bf16x8_t*)(feat_bf + i) = o;
    return;
  }
  if (bid < 2304) {  // ---- transposes
    const float* X; ushort* XT; int K, N, kb, nb, s;
    if (bid < 1280) {
      int r = bid - 256;  kb = r & 15; nb = (r >> 4) & 3;  s = r >> 6;
      X = W1; XT = W1T; K = F_; N = H_;
    } else {
      int r = bid - 1280; kb = r & 3;  nb = (r >> 2) & 15; s = r >> 6;
      X = W2; XT = W2T; K = H_; N = L_;
    }
    const int k0 = kb * 32, n0 = nb * 32;
    const int c = tid & 31, r0 = tid >> 5;
    const float* Xs = X + (size_t)s * K * N;
    ushort* XTs = XT + (size_t)s * N * K;
#pragma unroll
    for (int j = 0; j < 4; ++j)
      tile[r0 + 8 * j][c] = Xs[(size_t)(k0 + r0 + 8 * j) * N + n0 + c];
    __syncthreads();
#pragma unroll
    for (int j = 0; j < 4; ++j)
      XTs[(size_t)(n0 + r0 + 8 * j) * K + k0 + c] = f2bf(tile[c][r0 + 8 * j]);
    return;
  }
  {  // ---- softmax of 32 rows -> LDS transpose -> coalesced lpT[t][c][l]
    int bid2 = bid - 2304;                 // [0,256)
    int t = bid2 >> 4, l0 = (bid2 & 15) << 5;
    int lane = tid & 63;
#pragma unroll
    for (int p = 0; p < 8; ++p) {
      int rl = p * 4 + (tid >> 6);
      const float* x = pi + (size_t)(t * L_ + l0 + rl) * C_;
      float v0 = (lane < C_) ? x[lane] : -1e30f;
      float v1 = (lane + 64 < C_) ? x[lane + 64] : -1e30f;
      float m = fmaxf(v0, v1);
#pragma unroll
      for (int off = 32; off; off >>= 1) m = fmaxf(m, __shfl_xor(m, off, 64));
      float e0 = __expf(v0 - m);
      float e1 = (lane + 64 < C_) ? __expf(v1 - m) : 0.0f;
      float sm = e0 + e1;
#pragma unroll
      for (int off = 32; off; off >>= 1) sm += __shfl_xor(sm, off, 64);
      float inv = 1.0f / sm;
      if (lane < C_) tileT[lane][rl] = f2bf(e0 * inv);
      int c2 = lane + 64;
      if (c2 < CP_) tileT[c2][rl] = f2bf(c2 < C_ ? e1 * inv : 0.0f);
    }
    __syncthreads();
    ushort* dst = lpT + (size_t)t * CP_ * L_ + l0;
    for (int idx = tid; idx < 448; idx += 256) {       // 112 c x 4 chunks
      int c = idx >> 2, ch = (idx & 3) * 8;
      *(bf16x8_t*)(dst + (size_t)c * L_ + ch) = *(const bf16x8_t*)&tileT[c][ch];
    }
  }
}

// ---------------------------------------------------------------------------
// k12: ROUND-2 structure resurrected (fastest measured k12: every dispatch
// < 42 us).  Fully fused per (t, 32-row chunk): GEMM1+relu -> h_s,
// GEMM2+sigmoid -> p_s, tree routing -> mu (overwrites p_s), GEMM3 -> part.
// B-operands of all three GEMMs read DIRECT from global (L2-resident): the
// k-loops contain NO barriers, so the compiler software-pipelines loads
// with counted vmcnt (no barrier-forced drain).  5 __syncthreads total.
// Round-2's +19us total regression was its k_prep (64-block softmax), NOT
// this kernel -- misattributed in round 3.
// t = bid & 15: XCD x serves t in {x, x+8} -> per-XCD L2 set ~2 MB.
// ---------------------------------------------------------------------------
__global__ __launch_bounds__(256) void k12_mfma(
    const ushort* __restrict__ feat, const ushort* __restrict__ W1T,
    const float* __restrict__ b1, const ushort* __restrict__ W2T,
    const float* __restrict__ b2, const ushort* __restrict__ lpT,
    float* __restrict__ part) {
  __shared__ ushort smem[20992];                        // 41984 B
  ushort (*h_s)[136] = (ushort(*)[136])smem;            // [32][136] @0
  ushort (*u_s)[520] = (ushort(*)[520])(smem + 4352);   // A tile / p_s / mu

  const int bid = blockIdx.x;
  const int t = bid & 15, b0 = (bid >> 4) * 32;
  const int tid = threadIdx.x;
  const int w = tid >> 6, lane = tid & 63, quad = lane >> 4, n = lane & 15;

  // ---- stage feat A-tile (32x512) once ----
#pragma unroll
  for (int j = 0; j < 8; ++j) {
    int idx = j * 256 + tid;
    int row = idx >> 6, col8 = (idx & 63) * 8;
    *(bf16x8_t*)&u_s[row][col8] =
        *(const bf16x8_t*)(feat + (size_t)(b0 + row) * F_ + col8);
  }
  __syncthreads();                                       // B1

  // ---------------- GEMM1: h = relu(feat @ W1T^T + b1) ----------------
  {
    f32x4_t acc[2][2];
#pragma unroll
    for (int i = 0; i < 2; ++i)
#pragma unroll
      for (int j = 0; j < 2; ++j) acc[i][j] = (f32x4_t){0.f, 0.f, 0.f, 0.f};
    const ushort* Bp = W1T + ((size_t)t * H_ + w * 32 + n) * F_ + quad * 8;
#pragma unroll 4
    for (int k = 0; k < F_; k += 32) {
      bf16x8_t af[2], bfr[2];
      af[0] = *(const bf16x8_t*)&u_s[n][k + quad * 8];
      af[1] = *(const bf16x8_t*)&u_s[16 + n][k + quad * 8];
      bfr[0] = *(const bf16x8_t*)(Bp + k);
      bfr[1] = *(const bf16x8_t*)(Bp + 16 * F_ + k);
#pragma unroll
      for (int mt = 0; mt < 2; ++mt)
#pragma unroll
        for (int nt = 0; nt < 2; ++nt)
          acc[mt][nt] = __builtin_amdgcn_mfma_f32_16x16x32_bf16(
              af[mt], bfr[nt], acc[mt][nt], 0, 0, 0);
    }
    float bias[2] = {b1[t * H_ + w * 32 + n], b1[t * H_ + w * 32 + 16 + n]};
#pragma unroll
    for (int mt = 0; mt < 2; ++mt)
#pragma unroll
      for (int nt = 0; nt < 2; ++nt)
#pragma unroll
        for (int r = 0; r < 4; ++r) {
          int row = mt * 16 + quad * 4 + r;
          int col = w * 32 + nt * 16 + n;
          float v = acc[mt][nt][r] + bias[nt];
          h_s[row][col] = f2bf(v > 0.f ? v : 0.f);
        }
  }
  __syncthreads();                                       // B2

  // ---------------- GEMM2 + sigmoid -> p_s (aliases A tile) ----------------
  {
    bf16x8_t af2[2][4];                                  // A frags hoisted
#pragma unroll
    for (int mt = 0; mt < 2; ++mt)
#pragma unroll
      for (int ks = 0; ks < 4; ++ks)
        af2[mt][ks] = *(const bf16x8_t*)&h_s[mt * 16 + n][ks * 32 + quad * 8];
    const ushort* B2 = W2T + ((size_t)t * L_ + w * 16 + n) * H_ + quad * 8;
    for (int nc = 0; nc < 8; ++nc) {
      f32x4_t acc[2];
      acc[0] = (f32x4_t){0.f, 0.f, 0.f, 0.f};
      acc[1] = (f32x4_t){0.f, 0.f, 0.f, 0.f};
#pragma unroll
      for (int ks = 0; ks < 4; ++ks) {
        bf16x8_t bfrag = *(const bf16x8_t*)(B2 + (size_t)nc * 64 * H_ + ks * 32);
        acc[0] = __builtin_amdgcn_mfma_f32_16x16x32_bf16(af2[0][ks], bfrag,
                                                         acc[0], 0, 0, 0);
        acc[1] = __builtin_amdgcn_mfma_f32_16x16x32_bf16(af2[1][ks], bfrag,
                                                         acc[1], 0, 0, 0);
      }
      int l = nc * 64 + w * 16 + n;
      float bias = b2[t * L_ + l];
#pragma unroll
      for (int mt = 0; mt < 2; ++mt)
#pragma unroll
        for (int r = 0; r < 4; ++r) {
          float x = acc[mt][r] + bias;
          u_s[mt * 16 + quad * 4 + r][l] = f2bf(1.0f / (1.0f + __expf(-x)));
        }
    }
  }
  __syncthreads();                                       // B3

  // ---------------- routing: (row b, 16-leaf subtree s) -> mu in regs ----
  bf16x8_t mo[4][2];
#pragma unroll
  for (int pass = 0; pass < 4; ++pass) {
    int b = pass * 8 + (tid >> 5);
    int s = tid & 31;
    float P = 1.f;
#pragma unroll
    for (int d = 0; d < 5; ++d) {
      int nd = (1 << d) - 1 + (s >> (5 - d));
      int sd = (s >> (4 - d)) & 1;
      float pv = bf2f(u_s[b][nd]);
      P *= sd ? (1.f - pv) : pv;
    }
    float p5 = bf2f(u_s[b][31 + s]);
    float q5[2] = {P * p5, P * (1.f - p5)};
    float q6[4], q7[8];
#pragma unroll
    for (int j = 0; j < 2; ++j) {
      float pv = bf2f(u_s[b][63 + 2 * s + j]);
      q6[2 * j] = q5[j] * pv;
      q6[2 * j + 1] = q5[j] * (1.f - pv);
    }
#pragma unroll
    for (int u = 0; u < 4; ++u) {
      float pv = bf2f(u_s[b][127 + 4 * s + u]);
      q7[2 * u] = q6[u] * pv;
      q7[2 * u + 1] = q6[u] * (1.f - pv);
    }
    bf16x8_t o0, o1;
#pragma unroll
    for (int v = 0; v < 8; ++v) {
      float pv = bf2f(u_s[b][255 + 8 * s + v]);
      ushort e0 = f2bf(q7[v] * pv);
      ushort e1 = f2bf(q7[v] * (1.f - pv));
      if (v < 4) { o0[2 * v] = (short)e0; o0[2 * v + 1] = (short)e1; }
      else       { o1[2 * (v - 4)] = (short)e0; o1[2 * (v - 4) + 1] = (short)e1; }
    }
    mo[pass][0] = o0;
    mo[pass][1] = o1;
  }
  __syncthreads();                                       // B4
#pragma unroll
  for (int pass = 0; pass < 4; ++pass) {
    int b = pass * 8 + (tid >> 5);
    int s = tid & 31;
    *(bf16x8_t*)&u_s[b][s * 16]     = mo[pass][0];       // u_s now holds mu
    *(bf16x8_t*)&u_s[b][s * 16 + 8] = mo[pass][1];
  }
  __syncthreads();                                       // B5

  // ---------------- GEMM3: part[t][b][c] = mu @ leaf_p ----------------
  {
    const int mt = w >> 1;
    const int nt0 = (w & 1) * 4;
    const int ncnt = (w & 1) ? 3 : 4;
    const ushort* arow = &u_s[mt * 16 + n][0];
    const ushort* brow = lpT + (size_t)t * CP_ * L_ +
                         ((size_t)(nt0 * 16 + n)) * L_ + quad * 8;
    f32x4_t acc[4];
#pragma unroll
    for (int i = 0; i < 4; ++i) acc[i] = (f32x4_t){0.f, 0.f, 0.f, 0.f};
#pragma unroll 4
    for (int k = 0; k < L_; k += 32) {
      bf16x8_t af = *(const bf16x8_t*)(arow + k + quad * 8);
#pragma unroll
      for (int j = 0; j < 4; ++j) {
        if (j < ncnt) {
          bf16x8_t bfr = *(const bf16x8_t*)(brow + (size_t)j * 16 * L_ + k);
          acc[j] = __builtin_amdgcn_mfma_f32_16x16x32_bf16(af, bfr, acc[j],
                                                           0, 0, 0);
        }
      }
    }
    const int m0 = b0 + mt * 16 + quad * 4;
#pragma unroll
    for (int j = 0; j < 4; ++j) {
      int c = (nt0 + j) * 16 + n;
      if (j < ncnt && c < C_) {
#pragma unroll
        for (int r = 0; r < 4; ++r)
          part[((size_t)t * B_ + m0 + r) * C_ + c] = acc[j][r];
      }
    }
  }
}

// ---------------------------------------------------------------------------
// k6: out[b][c] = log( (sum_t part[t][b][c]) / (L*T) ), float4-vectorized
// (per-element sum order unchanged -> bit-identical).
// ---------------------------------------------------------------------------
__global__ __launch_bounds__(256) void k6_log(
    const float* __restrict__ part, float* __restrict__ out) {
  int i = (blockIdx.x * 256 + threadIdx.x) * 4;
  if (i < B_ * C_) {
    float4 s = {0.f, 0.f, 0.f, 0.f};
#pragma unroll
    for (int t = 0; t < T_; ++t) {
      float4 v = *(const float4*)(part + (size_t)t * B_ * C_ + i);
      s.x += v.x; s.y += v.y; s.z += v.z; s.w += v.w;
    }
    const float inv = 1.0f / (L_ * T_);
    float4 o;
    o.x = logf(s.x * inv); o.y = logf(s.y * inv);
    o.z = logf(s.z * inv); o.w = logf(s.w * inv);
    *(float4*)(out + i) = o;
  }
}

extern "C" void kernel_launch(void* const* d_in, const int* in_sizes, int n_in,
                              void* d_out, int out_size, void* d_ws,
                              size_t ws_size, hipStream_t stream) {
  const float* feat = (const float*)d_in[0];
  const float* W1   = (const float*)d_in[1];
  const float* b1   = (const float*)d_in[2];
  const float* W2   = (const float*)d_in[3];
  const float* b2   = (const float*)d_in[4];
  const float* pi   = (const float*)d_in[5];
  float* out = (float*)d_out;

  char* ws = (char*)d_ws;
  ushort* feat_bf  = (ushort*)(ws);                                // 1 MB
  ushort* W1T_buf  = (ushort*)(ws + ((size_t)1 << 20));            // 2 MB
  ushort* W2T_buf  = (ushort*)(ws + ((size_t)3 << 20));            // 2 MB
  ushort* lpT_buf  = (ushort*)(ws + ((size_t)5 << 20));            // 1.75 MB
  float*  part_buf = (float*)(ws + ((size_t)7 << 20));             // 6.25 MB

  k_prep<<<2560, 256, 0, stream>>>(feat, W1, W2, pi, feat_bf, W1T_buf,
                                   W2T_buf, lpT_buf);
  k12_mfma<<<512, 256, 0, stream>>>(feat_bf, W1T_buf, b1, W2T_buf, b2,
                                    lpT_buf, part_buf);
  k6_log<<<(B_ * C_ / 4 + 255) / 256, 256, 0, stream>>>(part_buf, out);
}

// Round 8
// 108.986 us; speedup vs baseline: 1.0625x; 1.0625x over previous
//
#include <hip/hip_runtime.h>
#include <hip/hip_bf16.h>
#include <math.h>

#define T_ 16
#define B_ 1024
#define F_ 512
#define H_ 128
#define D_ 8
#define C_ 100
#define L_ 512
#define CP_ 112   // C padded to multiple of 16 for MFMA N

typedef __attribute__((ext_vector_type(8))) short bf16x8_t;
typedef __attribute__((ext_vector_type(4))) float f32x4_t;

__device__ inline ushort f2bf(float x) {
  __hip_bfloat16 b = __float2bfloat16(x);
  return *(ushort*)&b;
}
__device__ inline float bf2f(ushort u) {
  union { unsigned int i; float f; } v;
  v.i = ((unsigned int)u) << 16;
  return v.f;
}

// Raw barrier helpers: NO vmcnt drain (prefetch loads stay in flight).
// LDS ordering is enforced explicitly with lgkmcnt(0) before publishing.
__device__ inline void bar_raw() {
  asm volatile("" ::: "memory");
  __builtin_amdgcn_s_barrier();
  asm volatile("" ::: "memory");
}
__device__ inline void bar_publish_lds() {
  asm volatile("s_waitcnt lgkmcnt(0)" ::: "memory");
  __builtin_amdgcn_s_barrier();
  asm volatile("" ::: "memory");
}

// ---------------------------------------------------------------------------
// k_prep: round-3 version (fastest measured).  Block-range dispatch:
//   [0,256)      : feat fp32 -> bf16
//   [256,1280)   : W1 [t][F][H] -> W1T [t][H][F] bf16
//   [1280,2304)  : W2 [t][H][L] -> W2T [t][L][H] bf16
//   [2304,2560)  : softmax(pi) -> lpT[t][c][l], 256 blocks x 32 rows,
//                  coalesced 16B stores.
// ---------------------------------------------------------------------------
__global__ __launch_bounds__(256) void k_prep(
    const float* __restrict__ feat, const float* __restrict__ W1,
    const float* __restrict__ W2, const float* __restrict__ pi,
    ushort* __restrict__ feat_bf, ushort* __restrict__ W1T,
    ushort* __restrict__ W2T, ushort* __restrict__ lpT) {
  __shared__ ushort ubuf[112 * 48];                  // 10752 B, aliased
  float (*tile)[33] = (float(*)[33])ubuf;            // transpose path (4224 B)
  ushort (*tileT)[48] = (ushort(*)[48])ubuf;         // softmax path
  const int bid = blockIdx.x, tid = threadIdx.x;

  if (bid < 256) {  // ---- feat cvt
    int i = (bid * 256 + tid) * 8;
    float4 a = *(const float4*)(feat + i);
    float4 b = *(const float4*)(feat + i + 4);
    bf16x8_t o;
    o[0] = (short)f2bf(a.x); o[1] = (short)f2bf(a.y);
    o[2] = (short)f2bf(a.z); o[3] = (short)f2bf(a.w);
    o[4] = (short)f2bf(b.x); o[5] = (short)f2bf(b.y);
    o[6] = (short)f2bf(b.z); o[7] = (short)f2bf(b.w);
    *(bf16x8_t*)(feat_bf + i) = o;
    return;
  }
  if (bid < 2304) {  // ---- transposes
    const float* X; ushort* XT; int K, N, kb, nb, s;
    if (bid < 1280) {
      int r = bid - 256;  kb = r & 15; nb = (r >> 4) & 3;  s = r >> 6;
      X = W1; XT = W1T; K = F_; N = H_;
    } else {
      int r = bid - 1280; kb = r & 3;  nb = (r >> 2) & 15; s = r >> 6;
      X = W2; XT = W2T; K = H_; N = L_;
    }
    const int k0 = kb * 32, n0 = nb * 32;
    const int c = tid & 31, r0 = tid >> 5;
    const float* Xs = X + (size_t)s * K * N;
    ushort* XTs = XT + (size_t)s * N * K;
#pragma unroll
    for (int j = 0; j < 4; ++j)
      tile[r0 + 8 * j][c] = Xs[(size_t)(k0 + r0 + 8 * j) * N + n0 + c];
    __syncthreads();
#pragma unroll
    for (int j = 0; j < 4; ++j)
      XTs[(size_t)(n0 + r0 + 8 * j) * K + k0 + c] = f2bf(tile[c][r0 + 8 * j]);
    return;
  }
  {  // ---- softmax of 32 rows -> LDS transpose -> coalesced lpT[t][c][l]
    int bid2 = bid - 2304;                 // [0,256)
    int t = bid2 >> 4, l0 = (bid2 & 15) << 5;
    int lane = tid & 63;
#pragma unroll
    for (int p = 0; p < 8; ++p) {
      int rl = p * 4 + (tid >> 6);
      const float* x = pi + (size_t)(t * L_ + l0 + rl) * C_;
      float v0 = (lane < C_) ? x[lane] : -1e30f;
      float v1 = (lane + 64 < C_) ? x[lane + 64] : -1e30f;
      float m = fmaxf(v0, v1);
#pragma unroll
      for (int off = 32; off; off >>= 1) m = fmaxf(m, __shfl_xor(m, off, 64));
      float e0 = __expf(v0 - m);
      float e1 = (lane + 64 < C_) ? __expf(v1 - m) : 0.0f;
      float sm = e0 + e1;
#pragma unroll
      for (int off = 32; off; off >>= 1) sm += __shfl_xor(sm, off, 64);
      float inv = 1.0f / sm;
      if (lane < C_) tileT[lane][rl] = f2bf(e0 * inv);
      int c2 = lane + 64;
      if (c2 < CP_) tileT[c2][rl] = f2bf(c2 < C_ ? e1 * inv : 0.0f);
    }
    __syncthreads();
    ushort* dst = lpT + (size_t)t * CP_ * L_ + l0;
    for (int idx = tid; idx < 448; idx += 256) {       // 112 c x 4 chunks
      int c = idx >> 2, ch = (idx & 3) * 8;
      *(bf16x8_t*)(dst + (size_t)c * L_ + ch) = *(const bf16x8_t*)&tileT[c][ch];
    }
  }
}

// ---------------------------------------------------------------------------
// k12: r5 structure + T4 counted-vmcnt barriers + 2-deep prefetch.
// __syncthreads() compiles to `s_waitcnt vmcnt(0) lgkmcnt(0); s_barrier`,
// which DRAINED the T14 prefetch at all ~30 barriers (the m97 pathology).
// Staging loops now use raw s_barrier + explicit lgkmcnt(0) only; global
// prefetch loads survive across barriers, waited on by compiler-emitted
// COUNTED vmcnt at their ds_write use.  2 register sets (parity-indexed,
// fully unrolled -> static) hold chunks k+1, k+2 in flight.
// grid 512, 59392 B LDS, 2 blocks/CU, t = bid & 15 for XCD L2 affinity.
// ---------------------------------------------------------------------------
__global__ __launch_bounds__(256) void k12_mfma(
    const ushort* __restrict__ feat, const ushort* __restrict__ W1T,
    const float* __restrict__ b1, const ushort* __restrict__ W2T,
    const float* __restrict__ b2, const ushort* __restrict__ lpT,
    float* __restrict__ part) {
  __shared__ ushort smem[29696];                        // 59392 B
  ushort (*h_s)[136] = (ushort(*)[136])smem;            // [32][136] @0
  ushort (*a_s)[72]  = (ushort(*)[72])(smem + 4352);    // [32][72]  ph1
  ushort (*b_s)[72]  = (ushort(*)[72])(smem + 6656);    // [128][72] ph1
  ushort (*w_s)[136] = (ushort(*)[136])(smem + 4352);   // [64][136] ph2
  ushort (*p_s)[520] = (ushort(*)[520])(smem + 13056);  // [32][520] ph2 + mu

  const int bid = blockIdx.x;
  const int t = bid & 15, b0 = (bid >> 4) * 32;
  const int tid = threadIdx.x;
  const int w = tid >> 6, lane = tid & 63, quad = lane >> 4, n = lane & 15;

  const int arow = tid >> 3, acol = (tid & 7) * 8;      // ph1 staging map
  const ushort* featp = feat + (size_t)(b0 + arow) * F_ + acol;
  const ushort* w1p   = W1T + ((size_t)t * H_ + arow) * F_ + acol;

  // ---------------- phase 1: h tile (M=32, N=128, K=512) ----------------
  {
    f32x4_t acc[2][2];
#pragma unroll
    for (int i = 0; i < 2; ++i)
#pragma unroll
      for (int j = 0; j < 2; ++j) acc[i][j] = (f32x4_t){0.f, 0.f, 0.f, 0.f};

    bf16x8_t ra[2], rb[2][4];
    // chunk 0 -> set 0, stage immediately (exposed once)
    ra[0] = *(const bf16x8_t*)(featp);
#pragma unroll
    for (int i = 0; i < 4; ++i)
      rb[0][i] = *(const bf16x8_t*)(w1p + (size_t)i * 32 * F_);
    *(bf16x8_t*)&a_s[arow][acol] = ra[0];
#pragma unroll
    for (int i = 0; i < 4; ++i)
      *(bf16x8_t*)&b_s[i * 32 + arow][acol] = rb[0][i];
    bar_publish_lds();
    // prefetch chunk 1 -> set 1, chunk 2 -> set 0 (10 loads in flight)
    ra[1] = *(const bf16x8_t*)(featp + 64);
#pragma unroll
    for (int i = 0; i < 4; ++i)
      rb[1][i] = *(const bf16x8_t*)(w1p + (size_t)i * 32 * F_ + 64);
    ra[0] = *(const bf16x8_t*)(featp + 128);
#pragma unroll
    for (int i = 0; i < 4; ++i)
      rb[0][i] = *(const bf16x8_t*)(w1p + (size_t)i * 32 * F_ + 128);

#pragma unroll
    for (int kc = 0; kc < 8; ++kc) {
#pragma unroll
      for (int ks = 0; ks < 64; ks += 32) {
        bf16x8_t af[2], bfr[2];
#pragma unroll
        for (int mt = 0; mt < 2; ++mt)
          af[mt] = *(const bf16x8_t*)&a_s[mt * 16 + n][ks + quad * 8];
#pragma unroll
        for (int nt = 0; nt < 2; ++nt)
          bfr[nt] = *(const bf16x8_t*)&b_s[w * 32 + nt * 16 + n][ks + quad * 8];
#pragma unroll
        for (int mt = 0; mt < 2; ++mt)
#pragma unroll
          for (int nt = 0; nt < 2; ++nt)
            acc[mt][nt] = __builtin_amdgcn_mfma_f32_16x16x32_bf16(
                af[mt], bfr[nt], acc[mt][nt], 0, 0, 0);
      }
      bar_raw();                               // a_s/b_s reads consumed
      if (kc < 7) {
        const int p = (kc + 1) & 1;            // compile-time after unroll
        *(bf16x8_t*)&a_s[arow][acol] = ra[p];  // counted vmcnt via reg dep
#pragma unroll
        for (int i = 0; i < 4; ++i)
          *(bf16x8_t*)&b_s[i * 32 + arow][acol] = rb[p][i];
        bar_publish_lds();                     // chunk kc+1 visible
        if (kc < 6) {                          // refill with chunk kc+3
          ra[p] = *(const bf16x8_t*)(featp + (kc + 3) * 64);
#pragma unroll
          for (int i = 0; i < 4; ++i)
            rb[p][i] = *(const bf16x8_t*)(w1p + (size_t)i * 32 * F_ + (kc + 3) * 64);
        }
      }
    }
    float bias[2] = {b1[t * H_ + w * 32 + n], b1[t * H_ + w * 32 + 16 + n]};
#pragma unroll
    for (int mt = 0; mt < 2; ++mt)
#pragma unroll
      for (int nt = 0; nt < 2; ++nt)
#pragma unroll
        for (int r = 0; r < 4; ++r) {
          int row = mt * 16 + quad * 4 + r;
          int col = w * 32 + nt * 16 + n;
          float v = acc[mt][nt][r] + bias[nt];
          h_s[row][col] = f2bf(v > 0.f ? v : 0.f);   // h_s region: no hazard
        }
  }

  // ---------------- phase 2: GEMM2 + sigmoid -> p_s ----------------
  {
    const int wrow = tid >> 4, wcol = (tid & 15) * 8;
    const ushort* w2p = W2T + ((size_t)t * L_ + wrow) * H_ + wcol;
    bf16x8_t rw[2][4];
    // issue nc=0,1 W-loads NOW: fly under epilogue + barrier + af2 reads
#pragma unroll
    for (int i = 0; i < 4; ++i)
      rw[0][i] = *(const bf16x8_t*)(w2p + (size_t)(i * 16) * H_);
#pragma unroll
    for (int i = 0; i < 4; ++i)
      rw[1][i] = *(const bf16x8_t*)(w2p + (size_t)(64 + i * 16) * H_);
    bar_publish_lds();                         // h_s visible; ph1 staging dead

    bf16x8_t af2[2][4];                        // A frags hoisted
#pragma unroll
    for (int mt = 0; mt < 2; ++mt)
#pragma unroll
      for (int ks = 0; ks < 4; ++ks)
        af2[mt][ks] = *(const bf16x8_t*)&h_s[mt * 16 + n][ks * 32 + quad * 8];
#pragma unroll
    for (int i = 0; i < 4; ++i)
      *(bf16x8_t*)&w_s[i * 16 + wrow][wcol] = rw[0][i];
    bar_publish_lds();                         // w_s(0) visible
#pragma unroll
    for (int i = 0; i < 4; ++i)                // refill set0 with nc=2
      rw[0][i] = *(const bf16x8_t*)(w2p + (size_t)(128 + i * 16) * H_);

#pragma unroll
    for (int nc = 0; nc < 8; ++nc) {
      f32x4_t acc[2];
      acc[0] = (f32x4_t){0.f, 0.f, 0.f, 0.f};
      acc[1] = (f32x4_t){0.f, 0.f, 0.f, 0.f};
#pragma unroll
      for (int ks = 0; ks < 4; ++ks) {
        bf16x8_t bfrag = *(const bf16x8_t*)&w_s[w * 16 + n][ks * 32 + quad * 8];
        acc[0] = __builtin_amdgcn_mfma_f32_16x16x32_bf16(af2[0][ks], bfrag,
                                                         acc[0], 0, 0, 0);
        acc[1] = __builtin_amdgcn_mfma_f32_16x16x32_bf16(af2[1][ks], bfrag,
                                                         acc[1], 0, 0, 0);
      }
      int l = nc * 64 + w * 16 + n;
      float bias = b2[t * L_ + l];
#pragma unroll
      for (int mt = 0; mt < 2; ++mt)
#pragma unroll
        for (int r = 0; r < 4; ++r) {
          float x = acc[mt][r] + bias;
          p_s[mt * 16 + quad * 4 + r][l] = f2bf(1.0f / (1.0f + __expf(-x)));
        }
      bar_raw();                               // w_s reads consumed
      if (nc < 7) {
        const int p = (nc + 1) & 1;
#pragma unroll
        for (int i = 0; i < 4; ++i)
          *(bf16x8_t*)&w_s[i * 16 + wrow][wcol] = rw[p][i];
        bar_publish_lds();                     // w_s(nc+1) visible
        if (nc < 6) {
#pragma unroll
          for (int i = 0; i < 4; ++i)
            rw[p][i] = *(const bf16x8_t*)(w2p + (size_t)((nc + 3) * 64 + i * 16) * H_);
        }
      }
    }
  }
  bar_publish_lds();                           // p_s complete for routing

  // ---------------- routing: (row b, 16-leaf subtree s) -> mu in regs ----
  bf16x8_t mo[4][2];
#pragma unroll
  for (int pass = 0; pass < 4; ++pass) {
    int b = pass * 8 + (tid >> 5);
    int s = tid & 31;
    float P = 1.f;
#pragma unroll
    for (int d = 0; d < 5; ++d) {
      int nd = (1 << d) - 1 + (s >> (5 - d));
      int sd = (s >> (4 - d)) & 1;
      float pv = bf2f(p_s[b][nd]);
      P *= sd ? (1.f - pv) : pv;
    }
    float p5 = bf2f(p_s[b][31 + s]);
    float q5[2] = {P * p5, P * (1.f - p5)};
    float q6[4], q7[8];
#pragma unroll
    for (int j = 0; j < 2; ++j) {
      float pv = bf2f(p_s[b][63 + 2 * s + j]);
      q6[2 * j] = q5[j] * pv;
      q6[2 * j + 1] = q5[j] * (1.f - pv);
    }
#pragma unroll
    for (int u = 0; u < 4; ++u) {
      float pv = bf2f(p_s[b][127 + 4 * s + u]);
      q7[2 * u] = q6[u] * pv;
      q7[2 * u + 1] = q6[u] * (1.f - pv);
    }
    bf16x8_t o0, o1;
#pragma unroll
    for (int v = 0; v < 8; ++v) {
      float pv = bf2f(p_s[b][255 + 8 * s + v]);
      ushort e0 = f2bf(q7[v] * pv);
      ushort e1 = f2bf(q7[v] * (1.f - pv));
      if (v < 4) { o0[2 * v] = (short)e0; o0[2 * v + 1] = (short)e1; }
      else       { o1[2 * (v - 4)] = (short)e0; o1[2 * (v - 4) + 1] = (short)e1; }
    }
    mo[pass][0] = o0;
    mo[pass][1] = o1;
  }
  bar_raw();         // routing reads consumed -> safe to overwrite p_s
#pragma unroll
  for (int pass = 0; pass < 4; ++pass) {
    int b = pass * 8 + (tid >> 5);
    int s = tid & 31;
    *(bf16x8_t*)&p_s[b][s * 16]     = mo[pass][0];   // p_s now holds mu
    *(bf16x8_t*)&p_s[b][s * 16 + 8] = mo[pass][1];
  }
  bar_publish_lds();

  // ---------------- GEMM3: part[t][b][c] = mu @ leaf_p (M=32,N=112,K=512) --
  {
    const int mt = w >> 1;
    const int nt0 = (w & 1) * 4;
    const int ncnt = (w & 1) ? 3 : 4;
    const ushort* arow2 = &p_s[mt * 16 + n][0];
    const ushort* brow = lpT + (size_t)t * CP_ * L_ +
                         ((size_t)(nt0 * 16 + n)) * L_ + quad * 8;
    f32x4_t acc[4];
#pragma unroll
    for (int i = 0; i < 4; ++i) acc[i] = (f32x4_t){0.f, 0.f, 0.f, 0.f};
#pragma unroll 4
    for (int k = 0; k < L_; k += 32) {
      bf16x8_t af = *(const bf16x8_t*)(arow2 + k + quad * 8);
#pragma unroll
      for (int j = 0; j < 4; ++j) {
        if (j < ncnt) {
          bf16x8_t bfr = *(const bf16x8_t*)(brow + (size_t)j * 16 * L_ + k);
          acc[j] = __builtin_amdgcn_mfma_f32_16x16x32_bf16(af, bfr, acc[j],
                                                           0, 0, 0);
        }
      }
    }
    const int m0 = b0 + mt * 16 + quad * 4;
#pragma unroll
    for (int j = 0; j < 4; ++j) {
      int c = (nt0 + j) * 16 + n;
      if (j < ncnt && c < C_) {
#pragma unroll
        for (int r = 0; r < 4; ++r)
          part[((size_t)t * B_ + m0 + r) * C_ + c] = acc[j][r];
      }
    }
  }
}

// ---------------------------------------------------------------------------
// k6: out[b][c] = log( (sum_t part[t][b][c]) / (L*T) ), float4-vectorized
// (per-element sum order unchanged -> bit-identical).
// ---------------------------------------------------------------------------
__global__ __launch_bounds__(256) void k6_log(
    const float* __restrict__ part, float* __restrict__ out) {
  int i = (blockIdx.x * 256 + threadIdx.x) * 4;
  if (i < B_ * C_) {
    float4 s = {0.f, 0.f, 0.f, 0.f};
#pragma unroll
    for (int t = 0; t < T_; ++t) {
      float4 v = *(const float4*)(part + (size_t)t * B_ * C_ + i);
      s.x += v.x; s.y += v.y; s.z += v.z; s.w += v.w;
    }
    const float inv = 1.0f / (L_ * T_);
    float4 o;
    o.x = logf(s.x * inv); o.y = logf(s.y * inv);
    o.z = logf(s.z * inv); o.w = logf(s.w * inv);
    *(float4*)(out + i) = o;
  }
}

extern "C" void kernel_launch(void* const* d_in, const int* in_sizes, int n_in,
                              void* d_out, int out_size, void* d_ws,
                              size_t ws_size, hipStream_t stream) {
  const float* feat = (const float*)d_in[0];
  const float* W1   = (const float*)d_in[1];
  const float* b1   = (const float*)d_in[2];
  const float* W2   = (const float*)d_in[3];
  const float* b2   = (const float*)d_in[4];
  const float* pi   = (const float*)d_in[5];
  float* out = (float*)d_out;

  char* ws = (char*)d_ws;
  ushort* feat_bf  = (ushort*)(ws);                                // 1 MB
  ushort* W1T_buf  = (ushort*)(ws + ((size_t)1 << 20));            // 2 MB
  ushort* W2T_buf  = (ushort*)(ws + ((size_t)3 << 20));            // 2 MB
  ushort* lpT_buf  = (ushort*)(ws + ((size_t)5 << 20));            // 1.75 MB
  float*  part_buf = (float*)(ws + ((size_t)7 << 20));             // 6.25 MB

  k_prep<<<2560, 256, 0, stream>>>(feat, W1, W2, pi, feat_bf, W1T_buf,
                                   W2T_buf, lpT_buf);
  k12_mfma<<<512, 256, 0, stream>>>(feat_bf, W1T_buf, b1, W2T_buf, b2,
                                    lpT_buf, part_buf);
  k6_log<<<(B_ * C_ / 4 + 255) / 256, 256, 0, stream>>>(part_buf, out);
}

// Round 9
// 108.448 us; speedup vs baseline: 1.0677x; 1.0050x over previous
//
#include <hip/hip_runtime.h>
#include <hip/hip_bf16.h>
#include <math.h>

#define T_ 16
#define B_ 1024
#define F_ 512
#define H_ 128
#define D_ 8
#define C_ 100
#define L_ 512
#define CP_ 112   // C padded to multiple of 16 for MFMA N

typedef __attribute__((ext_vector_type(8))) short bf16x8_t;
typedef __attribute__((ext_vector_type(4))) float f32x4_t;

__device__ inline ushort f2bf(float x) {
  __hip_bfloat16 b = __float2bfloat16(x);
  return *(ushort*)&b;
}
__device__ inline float bf2f(ushort u) {
  union { unsigned int i; float f; } v;
  v.i = ((unsigned int)u) << 16;
  return v.f;
}

// Raw barrier helpers: NO vmcnt drain (prefetch loads stay in flight).
__device__ inline void bar_raw() {
  asm volatile("" ::: "memory");
  __builtin_amdgcn_s_barrier();
  asm volatile("" ::: "memory");
}
__device__ inline void bar_publish_lds() {
  asm volatile("s_waitcnt lgkmcnt(0)" ::: "memory");
  __builtin_amdgcn_s_barrier();
  asm volatile("" ::: "memory");
}

// ---------------------------------------------------------------------------
// k_prep: unchanged (round-3 version, fastest measured).
// ---------------------------------------------------------------------------
__global__ __launch_bounds__(256) void k_prep(
    const float* __restrict__ feat, const float* __restrict__ W1,
    const float* __restrict__ W2, const float* __restrict__ pi,
    ushort* __restrict__ feat_bf, ushort* __restrict__ W1T,
    ushort* __restrict__ W2T, ushort* __restrict__ lpT) {
  __shared__ ushort ubuf[112 * 48];                  // 10752 B, aliased
  float (*tile)[33] = (float(*)[33])ubuf;            // transpose path (4224 B)
  ushort (*tileT)[48] = (ushort(*)[48])ubuf;         // softmax path
  const int bid = blockIdx.x, tid = threadIdx.x;

  if (bid < 256) {  // ---- feat cvt
    int i = (bid * 256 + tid) * 8;
    float4 a = *(const float4*)(feat + i);
    float4 b = *(const float4*)(feat + i + 4);
    bf16x8_t o;
    o[0] = (short)f2bf(a.x); o[1] = (short)f2bf(a.y);
    o[2] = (short)f2bf(a.z); o[3] = (short)f2bf(a.w);
    o[4] = (short)f2bf(b.x); o[5] = (short)f2bf(b.y);
    o[6] = (short)f2bf(b.z); o[7] = (short)f2bf(b.w);
    *(bf16x8_t*)(feat_bf + i) = o;
    return;
  }
  if (bid < 2304) {  // ---- transposes
    const float* X; ushort* XT; int K, N, kb, nb, s;
    if (bid < 1280) {
      int r = bid - 256;  kb = r & 15; nb = (r >> 4) & 3;  s = r >> 6;
      X = W1; XT = W1T; K = F_; N = H_;
    } else {
      int r = bid - 1280; kb = r & 3;  nb = (r >> 2) & 15; s = r >> 6;
      X = W2; XT = W2T; K = H_; N = L_;
    }
    const int k0 = kb * 32, n0 = nb * 32;
    const int c = tid & 31, r0 = tid >> 5;
    const float* Xs = X + (size_t)s * K * N;
    ushort* XTs = XT + (size_t)s * N * K;
#pragma unroll
    for (int j = 0; j < 4; ++j)
      tile[r0 + 8 * j][c] = Xs[(size_t)(k0 + r0 + 8 * j) * N + n0 + c];
    __syncthreads();
#pragma unroll
    for (int j = 0; j < 4; ++j)
      XTs[(size_t)(n0 + r0 + 8 * j) * K + k0 + c] = f2bf(tile[c][r0 + 8 * j]);
    return;
  }
  {  // ---- softmax of 32 rows -> LDS transpose -> coalesced lpT[t][c][l]
    int bid2 = bid - 2304;                 // [0,256)
    int t = bid2 >> 4, l0 = (bid2 & 15) << 5;
    int lane = tid & 63;
#pragma unroll
    for (int p = 0; p < 8; ++p) {
      int rl = p * 4 + (tid >> 6);
      const float* x = pi + (size_t)(t * L_ + l0 + rl) * C_;
      float v0 = (lane < C_) ? x[lane] : -1e30f;
      float v1 = (lane + 64 < C_) ? x[lane + 64] : -1e30f;
      float m = fmaxf(v0, v1);
#pragma unroll
      for (int off = 32; off; off >>= 1) m = fmaxf(m, __shfl_xor(m, off, 64));
      float e0 = __expf(v0 - m);
      float e1 = (lane + 64 < C_) ? __expf(v1 - m) : 0.0f;
      float sm = e0 + e1;
#pragma unroll
      for (int off = 32; off; off >>= 1) sm += __shfl_xor(sm, off, 64);
      float inv = 1.0f / sm;
      if (lane < C_) tileT[lane][rl] = f2bf(e0 * inv);
      int c2 = lane + 64;
      if (c2 < CP_) tileT[c2][rl] = f2bf(c2 < C_ ? e1 * inv : 0.0f);
    }
    __syncthreads();
    ushort* dst = lpT + (size_t)t * CP_ * L_ + l0;
    for (int idx = tid; idx < 448; idx += 256) {       // 112 c x 4 chunks
      int c = idx >> 2, ch = (idx & 3) * 8;
      *(bf16x8_t*)(dst + (size_t)c * L_ + ch) = *(const bf16x8_t*)&tileT[c][ch];
    }
  }
}

// ---------------------------------------------------------------------------
// k12: r8's T4 counted-vmcnt structure, widened to 512-thread blocks
// (8 waves).  Same grid (512 blocks), same per-block staging traffic,
// but 16 waves/CU (4/SIMD) instead of 8 -- double the TLP available to
// hide the residual latency (r8: MfmaUtil 4%, grid-limited occupancy).
// Wave->tile maps re-cut for 8 waves; per-output-element MFMA order
// unchanged -> bit-identical results.
// ---------------------------------------------------------------------------
__global__ __launch_bounds__(512, 4) void k12_mfma(
    const ushort* __restrict__ feat, const ushort* __restrict__ W1T,
    const float* __restrict__ b1, const ushort* __restrict__ W2T,
    const float* __restrict__ b2, const ushort* __restrict__ lpT,
    float* __restrict__ part) {
  __shared__ ushort smem[29696];                        // 59392 B
  ushort (*h_s)[136] = (ushort(*)[136])smem;            // [32][136] @0
  ushort (*a_s)[72]  = (ushort(*)[72])(smem + 4352);    // [32][72]  ph1
  ushort (*b_s)[72]  = (ushort(*)[72])(smem + 6656);    // [128][72] ph1
  ushort (*w_s)[136] = (ushort(*)[136])(smem + 4352);   // [64][136] ph2
  ushort (*p_s)[520] = (ushort(*)[520])(smem + 13056);  // [32][520] ph2 + mu

  const int bid = blockIdx.x;
  const int t = bid & 15, b0 = (bid >> 4) * 32;
  const int tid = threadIdx.x;                          // [0,512)
  const int w = tid >> 6, lane = tid & 63, quad = lane >> 4, n = lane & 15;

  // ph1 staging maps: A handled by tid<256 (1 unit), B by all (2 units).
  const bool doA = tid < 256;
  const int srow = tid >> 3, scol = (tid & 7) * 8;      // srow in [0,64)
  const ushort* featp = feat + (size_t)(b0 + srow) * F_ + scol;   // tid<256
  const ushort* w1p   = W1T + ((size_t)t * H_ + srow) * F_ + scol;

  // ---------------- phase 1: h tile (M=32, N=128, K=512) ----------------
  {
    f32x4_t acc[2];
    acc[0] = (f32x4_t){0.f, 0.f, 0.f, 0.f};
    acc[1] = (f32x4_t){0.f, 0.f, 0.f, 0.f};

    bf16x8_t ra[2], rb[2][2];
    // chunk 0 -> set 0, stage immediately (exposed once)
    if (doA) ra[0] = *(const bf16x8_t*)(featp);
#pragma unroll
    for (int i = 0; i < 2; ++i)
      rb[0][i] = *(const bf16x8_t*)(w1p + (size_t)i * 64 * F_);
    if (doA) *(bf16x8_t*)&a_s[srow][scol] = ra[0];
#pragma unroll
    for (int i = 0; i < 2; ++i)
      *(bf16x8_t*)&b_s[i * 64 + srow][scol] = rb[0][i];
    bar_publish_lds();
    // prefetch chunk 1 -> set 1, chunk 2 -> set 0
    if (doA) ra[1] = *(const bf16x8_t*)(featp + 64);
#pragma unroll
    for (int i = 0; i < 2; ++i)
      rb[1][i] = *(const bf16x8_t*)(w1p + (size_t)i * 64 * F_ + 64);
    if (doA) ra[0] = *(const bf16x8_t*)(featp + 128);
#pragma unroll
    for (int i = 0; i < 2; ++i)
      rb[0][i] = *(const bf16x8_t*)(w1p + (size_t)i * 64 * F_ + 128);

#pragma unroll
    for (int kc = 0; kc < 8; ++kc) {
#pragma unroll
      for (int ks = 0; ks < 64; ks += 32) {
        bf16x8_t af0 = *(const bf16x8_t*)&a_s[n][ks + quad * 8];
        bf16x8_t af1 = *(const bf16x8_t*)&a_s[16 + n][ks + quad * 8];
        bf16x8_t bfr = *(const bf16x8_t*)&b_s[w * 16 + n][ks + quad * 8];
        acc[0] = __builtin_amdgcn_mfma_f32_16x16x32_bf16(af0, bfr, acc[0],
                                                         0, 0, 0);
        acc[1] = __builtin_amdgcn_mfma_f32_16x16x32_bf16(af1, bfr, acc[1],
                                                         0, 0, 0);
      }
      bar_raw();                               // a_s/b_s reads consumed
      if (kc < 7) {
        const int p = (kc + 1) & 1;            // compile-time after unroll
        if (doA) *(bf16x8_t*)&a_s[srow][scol] = ra[p];
#pragma unroll
        for (int i = 0; i < 2; ++i)
          *(bf16x8_t*)&b_s[i * 64 + srow][scol] = rb[p][i];
        bar_publish_lds();                     // chunk kc+1 visible
        if (kc < 6) {                          // refill with chunk kc+3
          if (doA) ra[p] = *(const bf16x8_t*)(featp + (kc + 3) * 64);
#pragma unroll
          for (int i = 0; i < 2; ++i)
            rb[p][i] = *(const bf16x8_t*)(w1p + (size_t)i * 64 * F_ + (kc + 3) * 64);
        }
      }
    }
    float bias = b1[t * H_ + w * 16 + n];
#pragma unroll
    for (int mt = 0; mt < 2; ++mt)
#pragma unroll
      for (int r = 0; r < 4; ++r) {
        int row = mt * 16 + quad * 4 + r;
        float v = acc[mt][r] + bias;
        h_s[row][w * 16 + n] = f2bf(v > 0.f ? v : 0.f);
      }
  }

  // ---------------- phase 2: GEMM2 + sigmoid -> p_s ----------------
  {
    const int wrow = tid >> 4, wcol = (tid & 15) * 8;  // wrow in [0,32)
    const ushort* w2p = W2T + ((size_t)t * L_ + wrow) * H_ + wcol;
    bf16x8_t rw[2][2];
    // issue nc=0,1 W-loads NOW: fly under epilogue + barrier + af2 reads
#pragma unroll
    for (int i = 0; i < 2; ++i)
      rw[0][i] = *(const bf16x8_t*)(w2p + (size_t)(i * 32) * H_);
#pragma unroll
    for (int i = 0; i < 2; ++i)
      rw[1][i] = *(const bf16x8_t*)(w2p + (size_t)(64 + i * 32) * H_);
    bar_publish_lds();                         // h_s visible; ph1 staging dead

    const int mhalf = w >> 2, lhalf = w & 3;   // 2 m-halves x 4 l-tiles
    bf16x8_t af2[4];                           // A frags hoisted
#pragma unroll
    for (int ks = 0; ks < 4; ++ks)
      af2[ks] = *(const bf16x8_t*)&h_s[mhalf * 16 + n][ks * 32 + quad * 8];
#pragma unroll
    for (int i = 0; i < 2; ++i)
      *(bf16x8_t*)&w_s[i * 32 + wrow][wcol] = rw[0][i];
    bar_publish_lds();                         // w_s(0) visible
#pragma unroll
    for (int i = 0; i < 2; ++i)                // refill set0 with nc=2
      rw[0][i] = *(const bf16x8_t*)(w2p + (size_t)(128 + i * 32) * H_);

#pragma unroll
    for (int nc = 0; nc < 8; ++nc) {
      f32x4_t acc = (f32x4_t){0.f, 0.f, 0.f, 0.f};
#pragma unroll
      for (int ks = 0; ks < 4; ++ks) {
        bf16x8_t bfrag = *(const bf16x8_t*)&w_s[lhalf * 16 + n][ks * 32 + quad * 8];
        acc = __builtin_amdgcn_mfma_f32_16x16x32_bf16(af2[ks], bfrag, acc,
                                                      0, 0, 0);
      }
      int l = nc * 64 + lhalf * 16 + n;
      float bias = b2[t * L_ + l];
#pragma unroll
      for (int r = 0; r < 4; ++r) {
        float x = acc[r] + bias;
        p_s[mhalf * 16 + quad * 4 + r][l] = f2bf(1.0f / (1.0f + __expf(-x)));
      }
      bar_raw();                               // w_s reads consumed
      if (nc < 7) {
        const int p = (nc + 1) & 1;
#pragma unroll
        for (int i = 0; i < 2; ++i)
          *(bf16x8_t*)&w_s[i * 32 + wrow][wcol] = rw[p][i];
        bar_publish_lds();                     // w_s(nc+1) visible
        if (nc < 6) {
#pragma unroll
          for (int i = 0; i < 2; ++i)
            rw[p][i] = *(const bf16x8_t*)(w2p + (size_t)((nc + 3) * 64 + i * 32) * H_);
        }
      }
    }
  }
  bar_publish_lds();                           // p_s complete for routing

  // ---------------- routing: 1024 units (b,s) over 512 threads, 2 passes --
  bf16x8_t mo[2][2];
#pragma unroll
  for (int pass = 0; pass < 2; ++pass) {
    int unit = pass * 512 + tid;
    int b = unit >> 5;
    int s = unit & 31;
    float P = 1.f;
#pragma unroll
    for (int d = 0; d < 5; ++d) {
      int nd = (1 << d) - 1 + (s >> (5 - d));
      int sd = (s >> (4 - d)) & 1;
      float pv = bf2f(p_s[b][nd]);
      P *= sd ? (1.f - pv) : pv;
    }
    float p5 = bf2f(p_s[b][31 + s]);
    float q5[2] = {P * p5, P * (1.f - p5)};
    float q6[4], q7[8];
#pragma unroll
    for (int j = 0; j < 2; ++j) {
      float pv = bf2f(p_s[b][63 + 2 * s + j]);
      q6[2 * j] = q5[j] * pv;
      q6[2 * j + 1] = q5[j] * (1.f - pv);
    }
#pragma unroll
    for (int u = 0; u < 4; ++u) {
      float pv = bf2f(p_s[b][127 + 4 * s + u]);
      q7[2 * u] = q6[u] * pv;
      q7[2 * u + 1] = q6[u] * (1.f - pv);
    }
    bf16x8_t o0, o1;
#pragma unroll
    for (int v = 0; v < 8; ++v) {
      float pv = bf2f(p_s[b][255 + 8 * s + v]);
      ushort e0 = f2bf(q7[v] * pv);
      ushort e1 = f2bf(q7[v] * (1.f - pv));
      if (v < 4) { o0[2 * v] = (short)e0; o0[2 * v + 1] = (short)e1; }
      else       { o1[2 * (v - 4)] = (short)e0; o1[2 * (v - 4) + 1] = (short)e1; }
    }
    mo[pass][0] = o0;
    mo[pass][1] = o1;
  }
  bar_raw();         // routing reads consumed -> safe to overwrite p_s
#pragma unroll
  for (int pass = 0; pass < 2; ++pass) {
    int unit = pass * 512 + tid;
    int b = unit >> 5;
    int s = unit & 31;
    *(bf16x8_t*)&p_s[b][s * 16]     = mo[pass][0];   // p_s now holds mu
    *(bf16x8_t*)&p_s[b][s * 16 + 8] = mo[pass][1];
  }
  bar_publish_lds();

  // ---------------- GEMM3: part = mu @ leaf_p (M=32,N=112,K=512) ----------
  // 14 (mt,nt) units over 8 waves: wave w does unit w, and unit w+8 if w<6.
  {
#pragma unroll
    for (int uu = 0; uu < 2; ++uu) {
      int u = w + uu * 8;
      if (u < 14) {
        const int mt = u & 1, nt = u >> 1;
        const ushort* arow = &p_s[mt * 16 + n][0];
        const ushort* brow = lpT + (size_t)t * CP_ * L_ +
                             ((size_t)(nt * 16 + n)) * L_ + quad * 8;
        f32x4_t acc = (f32x4_t){0.f, 0.f, 0.f, 0.f};
#pragma unroll 4
        for (int k = 0; k < L_; k += 32) {
          bf16x8_t af = *(const bf16x8_t*)(arow + k + quad * 8);
          bf16x8_t bfr = *(const bf16x8_t*)(brow + k);
          acc = __builtin_amdgcn_mfma_f32_16x16x32_bf16(af, bfr, acc, 0, 0, 0);
        }
        const int m0 = b0 + mt * 16 + quad * 4;
        const int c = nt * 16 + n;
        if (c < C_) {
#pragma unroll
          for (int r = 0; r < 4; ++r)
            part[((size_t)t * B_ + m0 + r) * C_ + c] = acc[r];
        }
      }
    }
  }
}

// ---------------------------------------------------------------------------
// k6: out[b][c] = log( (sum_t part[t][b][c]) / (L*T) ), float4-vectorized.
// ---------------------------------------------------------------------------
__global__ __launch_bounds__(256) void k6_log(
    const float* __restrict__ part, float* __restrict__ out) {
  int i = (blockIdx.x * 256 + threadIdx.x) * 4;
  if (i < B_ * C_) {
    float4 s = {0.f, 0.f, 0.f, 0.f};
#pragma unroll
    for (int t = 0; t < T_; ++t) {
      float4 v = *(const float4*)(part + (size_t)t * B_ * C_ + i);
      s.x += v.x; s.y += v.y; s.z += v.z; s.w += v.w;
    }
    const float inv = 1.0f / (L_ * T_);
    float4 o;
    o.x = logf(s.x * inv); o.y = logf(s.y * inv);
    o.z = logf(s.z * inv); o.w = logf(s.w * inv);
    *(float4*)(out + i) = o;
  }
}

extern "C" void kernel_launch(void* const* d_in, const int* in_sizes, int n_in,
                              void* d_out, int out_size, void* d_ws,
                              size_t ws_size, hipStream_t stream) {
  const float* feat = (const float*)d_in[0];
  const float* W1   = (const float*)d_in[1];
  const float* b1   = (const float*)d_in[2];
  const float* W2   = (const float*)d_in[3];
  const float* b2   = (const float*)d_in[4];
  const float* pi   = (const float*)d_in[5];
  float* out = (float*)d_out;

  char* ws = (char*)d_ws;
  ushort* feat_bf  = (ushort*)(ws);                                // 1 MB
  ushort* W1T_buf  = (ushort*)(ws + ((size_t)1 << 20));            // 2 MB
  ushort* W2T_buf  = (ushort*)(ws + ((size_t)3 << 20));            // 2 MB
  ushort* lpT_buf  = (ushort*)(ws + ((size_t)5 << 20));            // 1.75 MB
  float*  part_buf = (float*)(ws + ((size_t)7 << 20));             // 6.25 MB

  k_prep<<<2560, 256, 0, stream>>>(feat, W1, W2, pi, feat_bf, W1T_buf,
                                   W2T_buf, lpT_buf);
  k12_mfma<<<512, 512, 0, stream>>>(feat_bf, W1T_buf, b1, W2T_buf, b2,
                                    lpT_buf, part_buf);
  k6_log<<<(B_ * C_ / 4 + 255) / 256, 256, 0, stream>>>(part_buf, out);
}